// Round 1
// baseline (5059.522 us; speedup 1.0000x reference)
//
#include <hip/hip_runtime.h>
#include <hip/hip_bf16.h>
#include <math.h>

#define TT 4096   // tokens = B*N
#define DD 1024
#define EE 8
#define FF 4096
#define EPSF 1e-7f

// ---------------------------------------------------------------------------
// Tiled fp32 GEMM: 128x128 tile, BK=8, 256 threads, 8x8 per thread.
// EPI 0: C[m][n] = A@B + bias                       (proj: P = x@Wp + bp)
// EPI 1: H[offs[e]+slot][n] = gelu(X[list]@W1e + b1e)   (expert up-proj, gather)
// EPI 2: atomicAdd(out[token][n], w * (H@W2e))          (expert down-proj, scatter)
// ---------------------------------------------------------------------------
template<int EPI>
__global__ __launch_bounds__(256)
void gemm128(const float* __restrict__ Abase, const float* __restrict__ Bbase,
             const float* __restrict__ bias, float* __restrict__ Cbase,
             const int* __restrict__ list_token, const float* __restrict__ list_w,
             const int* __restrict__ cnt, const int* __restrict__ offs,
             int K, int lda, int ldb)
{
    const int e = blockIdx.z;
    int M, cn = 0, of = 0;
    if constexpr (EPI == 0) { M = TT; }
    else { cn = cnt[e]; of = offs[e]; M = cn; }
    const int m0 = blockIdx.x * 128;
    if (m0 >= M) return;                       // uniform early exit (dead tiles)
    const int n0 = blockIdx.y * 128;

    const float* Bp = Bbase;
    if constexpr (EPI == 1) Bp += (size_t)e * DD * FF;
    if constexpr (EPI == 2) Bp += (size_t)e * FF * DD;

    __shared__ float As[8][128];   // transposed A tile: As[k][m]
    __shared__ float Bs[8][128];

    const int tid = threadIdx.x;
    const int tx = tid & 15, ty = tid >> 4;          // 16x16 thread grid, 8x8 each
    const int arow = tid >> 1, akq = (tid & 1) * 4;  // A staging: row, k-quad
    const int brow = tid >> 5, bn4 = (tid & 31) * 4; // B staging: k-row, n-quad

    // Resolve this thread's A source row once (gather for EPI1).
    const float* Arow;
    if constexpr (EPI == 0) {
        Arow = Abase + (size_t)(m0 + arow) * lda;
    } else if constexpr (EPI == 1) {
        int slot = m0 + arow; if (slot > cn - 1) slot = cn - 1;
        int tok = list_token[e * TT + slot];
        Arow = Abase + (size_t)tok * lda;
    } else {
        int slot = m0 + arow; if (slot > cn - 1) slot = cn - 1;
        Arow = Abase + (size_t)(of + slot) * lda;
    }
    const float* Brow = Bp + (size_t)brow * ldb + n0 + bn4;

    float acc[8][8];
#pragma unroll
    for (int i = 0; i < 8; ++i)
#pragma unroll
        for (int j = 0; j < 8; ++j) acc[i][j] = 0.f;

    for (int kk = 0; kk < K; kk += 8) {
        float4 a4 = *(const float4*)(Arow + kk + akq);
        float4 b4 = *(const float4*)(Brow + (size_t)kk * ldb);
        __syncthreads();                       // protect prior-iter LDS reads
        As[akq + 0][arow] = a4.x;
        As[akq + 1][arow] = a4.y;
        As[akq + 2][arow] = a4.z;
        As[akq + 3][arow] = a4.w;
        *(float4*)&Bs[brow][bn4] = b4;
        __syncthreads();
#pragma unroll
        for (int k = 0; k < 8; ++k) {
            float a[8], b[8];
            *(float4*)&a[0] = *(const float4*)&As[k][ty * 8];
            *(float4*)&a[4] = *(const float4*)&As[k][ty * 8 + 4];
            *(float4*)&b[0] = *(const float4*)&Bs[k][tx * 8];
            *(float4*)&b[4] = *(const float4*)&Bs[k][tx * 8 + 4];
#pragma unroll
            for (int i = 0; i < 8; ++i)
#pragma unroll
                for (int j = 0; j < 8; ++j)
                    acc[i][j] = fmaf(a[i], b[j], acc[i][j]);
        }
    }

    if constexpr (EPI == 0) {
#pragma unroll
        for (int i = 0; i < 8; ++i) {
            int m = m0 + ty * 8 + i;
            float* Crow = Cbase + (size_t)m * DD + n0 + tx * 8;
            float4 c0, c1;
            c0.x = acc[i][0] + bias[n0 + tx * 8 + 0];
            c0.y = acc[i][1] + bias[n0 + tx * 8 + 1];
            c0.z = acc[i][2] + bias[n0 + tx * 8 + 2];
            c0.w = acc[i][3] + bias[n0 + tx * 8 + 3];
            c1.x = acc[i][4] + bias[n0 + tx * 8 + 4];
            c1.y = acc[i][5] + bias[n0 + tx * 8 + 5];
            c1.z = acc[i][6] + bias[n0 + tx * 8 + 6];
            c1.w = acc[i][7] + bias[n0 + tx * 8 + 7];
            *(float4*)(Crow + 0) = c0;
            *(float4*)(Crow + 4) = c1;
        }
    } else if constexpr (EPI == 1) {
        const float* be = bias + (size_t)e * FF;
#pragma unroll
        for (int i = 0; i < 8; ++i) {
            int slot = m0 + ty * 8 + i;
            if (slot < cn) {
                float* Hrow = Cbase + (size_t)(of + slot) * FF + n0 + tx * 8;
                float4 c0, c1;
                float tmp[8];
#pragma unroll
                for (int j = 0; j < 8; ++j) {
                    float v = acc[i][j] + be[n0 + tx * 8 + j];
                    tmp[j] = 0.5f * v * (1.f + erff(v * 0.70710678118654752f));
                }
                c0.x = tmp[0]; c0.y = tmp[1]; c0.z = tmp[2]; c0.w = tmp[3];
                c1.x = tmp[4]; c1.y = tmp[5]; c1.z = tmp[6]; c1.w = tmp[7];
                *(float4*)(Hrow + 0) = c0;
                *(float4*)(Hrow + 4) = c1;
            }
        }
    } else {
#pragma unroll
        for (int i = 0; i < 8; ++i) {
            int slot = m0 + ty * 8 + i;
            if (slot < cn) {
                int tok = list_token[e * TT + slot];
                float w = list_w[e * TT + slot];
                float* orow = Cbase + (size_t)tok * DD + n0 + tx * 8;
#pragma unroll
                for (int j = 0; j < 8; ++j)
                    atomicAdd(&orow[j], acc[i][j] * w);
            }
        }
    }
}

// ---------------------------------------------------------------------------
// Routing: one wave per token. fp32 throughout (top-k selection must be exact).
// ---------------------------------------------------------------------------
__global__ __launch_bounds__(256)
void route_kernel(const float* __restrict__ P, const float* __restrict__ cent,
                  int* __restrict__ cnt, int* __restrict__ list_token,
                  float* __restrict__ list_w, int* __restrict__ tok_e,
                  float* __restrict__ tok_w)
{
    const int lane = threadIdx.x & 63;
    const int wv = threadIdx.x >> 6;
    const int t = blockIdx.x * 4 + wv;
    const float* p = P + (size_t)t * DD;

    float v[16];
    float s = 0.f;
#pragma unroll
    for (int j = 0; j < 4; ++j) {
        float4 f = *(const float4*)(p + j * 256 + lane * 4);
        v[j * 4 + 0] = f.x; v[j * 4 + 1] = f.y; v[j * 4 + 2] = f.z; v[j * 4 + 3] = f.w;
        s += f.x * f.x + f.y * f.y + f.z * f.z + f.w * f.w;
    }
    float cs[EE], dt[EE];
#pragma unroll
    for (int e = 0; e < EE; ++e) {
        const float* c = cent + (size_t)e * DD;
        float cse = 0.f, dte = 0.f;
#pragma unroll
        for (int j = 0; j < 4; ++j) {
            float4 f = *(const float4*)(c + j * 256 + lane * 4);
            cse += f.x * f.x + f.y * f.y + f.z * f.z + f.w * f.w;
            dte += f.x * v[j * 4 + 0] + f.y * v[j * 4 + 1]
                 + f.z * v[j * 4 + 2] + f.w * v[j * 4 + 3];
        }
        cs[e] = cse; dt[e] = dte;
    }
#pragma unroll
    for (int m = 1; m < 64; m <<= 1) {
        s += __shfl_xor(s, m);
#pragma unroll
        for (int e = 0; e < EE; ++e) {
            cs[e] += __shfl_xor(cs[e], m);
            dt[e] += __shfl_xor(dt[e], m);
        }
    }
    float norm = fmaxf(sqrtf(s), EPSF);
    float scale = norm > 0.95f ? 0.95f / norm : 1.0f;
    float xns = fminf(s * scale * scale, 0.99f);

    float best1 = -1e30f, best2 = -1e30f; int i1 = 0, i2 = 0;
#pragma unroll
    for (int e = 0; e < EE; ++e) {
        float cnorm = fmaxf(sqrtf(cs[e]), EPSF);
        float csc = cnorm > 0.95f ? 0.95f / cnorm : 1.0f;
        float cns = fminf(cs[e] * csc * csc, 0.99f);
        float dot = dt[e] * scale * csc;
        float diff = fmaxf(xns + cns - 2.f * dot, 0.f);
        float denom = (1.f - xns) * (1.f - cns) + 1e-7f;
        float arg = fmaxf(1.f + 2.f * diff / denom, 1.f + 1e-7f);
        float lg = -acoshf(arg);
        if (lg > best1) { best2 = best1; i2 = i1; best1 = lg; i1 = e; }
        else if (lg > best2) { best2 = lg; i2 = e; }
    }
    if (lane == 0) {
        float ex = expf(best2 - best1);      // softmax over top-2 (max-sub)
        float inv = 1.f / (1.f + ex);
        int s0 = atomicAdd(&cnt[i1], 1);
        int s1 = atomicAdd(&cnt[i2], 1);
        list_token[i1 * TT + s0] = t; list_w[i1 * TT + s0] = inv;
        list_token[i2 * TT + s1] = t; list_w[i2 * TT + s1] = ex * inv;
        tok_e[2 * t] = i1; tok_e[2 * t + 1] = i2;
        tok_w[2 * t] = inv; tok_w[2 * t + 1] = ex * inv;
    }
}

__global__ void offs_kernel(const int* __restrict__ cnt, int* __restrict__ offs)
{
    if (threadIdx.x == 0 && blockIdx.x == 0) {
        int a = 0;
        for (int e = 0; e < EE; ++e) { offs[e] = a; a += cnt[e]; }
    }
}

// out[t][d] = w0*b2[e0][d] + w1*b2[e1][d]  (also fully overwrites poisoned d_out)
__global__ __launch_bounds__(256)
void out_init(const int* __restrict__ tok_e, const float* __restrict__ tok_w,
              const float* __restrict__ b2, float* __restrict__ out)
{
    int idx = blockIdx.x * 256 + threadIdx.x;
    int t = idx >> 8;
    int d = (idx & 255) * 4;
    int e0 = tok_e[2 * t], e1 = tok_e[2 * t + 1];
    float w0 = tok_w[2 * t], w1 = tok_w[2 * t + 1];
    float4 a = *(const float4*)(b2 + (size_t)e0 * DD + d);
    float4 b = *(const float4*)(b2 + (size_t)e1 * DD + d);
    float4 o;
    o.x = w0 * a.x + w1 * b.x;
    o.y = w0 * a.y + w1 * b.y;
    o.z = w0 * a.z + w1 * b.z;
    o.w = w0 * a.w + w1 * b.w;
    *(float4*)(out + (size_t)t * DD + d) = o;
}

// ---------------------------------------------------------------------------
extern "C" void kernel_launch(void* const* d_in, const int* in_sizes, int n_in,
                              void* d_out, int out_size, void* d_ws, size_t ws_size,
                              hipStream_t stream)
{
    const float* x    = (const float*)d_in[0];
    const float* cent = (const float*)d_in[1];
    const float* Wp   = (const float*)d_in[2];
    const float* bp   = (const float*)d_in[3];
    const float* W1   = (const float*)d_in[4];
    const float* b1   = (const float*)d_in[5];
    const float* W2   = (const float*)d_in[6];
    const float* b2   = (const float*)d_in[7];
    float* out = (float*)d_out;

    char* ws = (char*)d_ws;
    size_t off = 0;
    float* H          = (float*)(ws + off); off += (size_t)2 * TT * FF * 4; // 134 MB
    float* P          = (float*)(ws + off); off += (size_t)TT * DD * 4;     // 16.8 MB
    int*   list_token = (int*)  (ws + off); off += (size_t)EE * TT * 4;
    float* list_w     = (float*)(ws + off); off += (size_t)EE * TT * 4;
    int*   tok_e      = (int*)  (ws + off); off += (size_t)TT * 2 * 4;
    float* tok_w      = (float*)(ws + off); off += (size_t)TT * 2 * 4;
    int*   cnt        = (int*)  (ws + off); off += 64;
    int*   offs       = (int*)  (ws + off); off += 64;
    if (ws_size < off) return;   // ws too small: leave d_out poisoned -> loud failure

    // ws is re-poisoned 0xAA before every timed launch: zero the counters.
    hipMemsetAsync(cnt, 0, EE * sizeof(int), stream);

    // 1) P = x @ Wp + bp
    gemm128<0><<<dim3(TT / 128, DD / 128, 1), 256, 0, stream>>>(
        x, Wp, bp, P, nullptr, nullptr, nullptr, nullptr, DD, DD, DD);
    // 2) hyperbolic routing -> top-2 lists
    route_kernel<<<TT / 4, 256, 0, stream>>>(P, cent, cnt, list_token, list_w,
                                             tok_e, tok_w);
    // 3) per-expert prefix offsets
    offs_kernel<<<1, 64, 0, stream>>>(cnt, offs);
    // 4) out = w0*b2[e0] + w1*b2[e1]
    out_init<<<TT, 256, 0, stream>>>(tok_e, tok_w, b2, out);
    // 5) H = gelu(gather(x) @ W1[e] + b1[e])
    gemm128<1><<<dim3(TT / 128, FF / 128, EE), 256, 0, stream>>>(
        x, W1, b1, H, list_token, nullptr, cnt, offs, DD, DD, FF);
    // 6) out += w * (H @ W2[e])   (atomic scatter)
    gemm128<2><<<dim3(TT / 128, DD / 128, EE), 256, 0, stream>>>(
        H, W2, nullptr, out, list_token, list_w, cnt, offs, FF, FF, DD);
}

// Round 2
// 2815.893 us; speedup vs baseline: 1.7968x; 1.7968x over previous
//
#include <hip/hip_runtime.h>
#include <hip/hip_bf16.h>
#include <math.h>

#define TT 4096   // tokens = B*N
#define DD 1024
#define EE 8
#define FF 4096
#define EPSF 1e-7f

typedef __attribute__((ext_vector_type(4))) float  f32x4;
typedef __attribute__((ext_vector_type(8))) short  short8;   // 8 bf16 (MFMA A/B frag)
typedef __attribute__((ext_vector_type(4))) short  short4v;  // 4 bf16 (b64 LDS write)

__device__ __forceinline__ unsigned short bf16_rne(float f) {
    unsigned u = __float_as_uint(f);
    return (unsigned short)((u + 0x7fffu + ((u >> 16) & 1u)) >> 16);
}
__device__ __forceinline__ float bf16f(unsigned short h) {
    return __uint_as_float(((unsigned)h) << 16);
}
// split x into hi+lo bf16 (hi = RNE(x), lo = RNE(x - hi)): ~16 mantissa bits total
#define SPLIT(x, H, L) { unsigned short _h = bf16_rne(x); H = (short)_h; \
                         L = (short)bf16_rne((x) - bf16f(_h)); }

// ---------------------------------------------------------------------------
// Grouped split-bf16 MFMA GEMM. 128x128 tile, BK=32, 256 thr = 4 waves (2x2),
// wave tile 64x64 = 4x4 frags of 16x16. C = Ah*Bh + Ah*Bl + Al*Bh (fp32 acc).
// LDS layout per tile: [row][32 k] bf16, 64B rows = 4x16B slots, slot XOR
// swizzle (slot ^ ((row>>2)&3)) -> frag ds_read_b128 is 2-way (free).
// EPI 1: H[of+slot][n] = gelu(x[list]@W1e + b1e)     (gather rows of x)
// EPI 2: atomicAdd(out[tok][n], w * (H@W2e))         (scatter by token)
// ---------------------------------------------------------------------------
template<int EPI>
__global__ __launch_bounds__(256, 2)
void moe_gemm(const float* __restrict__ Abase, const float* __restrict__ Bbase,
              const float* __restrict__ bias, float* __restrict__ Cbase,
              const int* __restrict__ list_token, const float* __restrict__ list_w,
              const int* __restrict__ cnt, const int* __restrict__ offs,
              int K, int lda, int ldb)
{
    const int e = blockIdx.z;
    const int cn = cnt[e], of = offs[e];
    const int m0 = blockIdx.x * 128;
    if (m0 >= cn) return;                    // uniform early exit
    const int n0 = blockIdx.y * 128;
    const float* Bp = Bbase + (EPI == 1 ? (size_t)e * DD * FF : (size_t)e * FF * DD);

    __shared__ __align__(16) short AsHi[128 * 32];
    __shared__ __align__(16) short AsLo[128 * 32];
    __shared__ __align__(16) short BsHi[128 * 32];
    __shared__ __align__(16) short BsLo[128 * 32];
    __shared__ int   blkTok[128];
    __shared__ float blkW[128];

    const int tid = threadIdx.x;
    const int arow = tid >> 1, ahalf = tid & 1;          // A stage: row, 16-k half
    const int bn4 = (tid & 31) * 4, bk4 = (tid >> 5) * 4; // B stage: 4n x 4k block

    // resolve this thread's A source row once (gather for EPI1, H rows for EPI2)
    const float* Arow;
    {
        int slot = m0 + arow; if (slot > cn - 1) slot = cn - 1;
        if constexpr (EPI == 1) Arow = Abase + (size_t)list_token[e * TT + slot] * lda;
        else                    Arow = Abase + (size_t)(of + slot) * lda;
    }
    if constexpr (EPI == 2) {
        if (tid < 128) {                      // per-row (token, weight) for epilogue
            int s = m0 + tid; if (s > cn - 1) s = cn - 1;
            blkTok[tid] = list_token[e * TT + s];
            blkW[tid]   = list_w[e * TT + s];
        }
    }

    const int lane = tid & 63, wv = tid >> 6;
    const int wr = wv >> 1, wc = wv & 1;      // wave -> 64x64 sub-tile
    const int fr = lane & 15, fq = lane >> 4; // frag row/col, k-group

    f32x4 acc[4][4];
#pragma unroll
    for (int i = 0; i < 4; ++i)
#pragma unroll
        for (int j = 0; j < 4; ++j) acc[i][j] = (f32x4)0.f;

    for (int kk = 0; kk < K; kk += 32) {
        // ---- global loads (independent of LDS; overlap with prior MFMA) ----
        f32x4 av0 = *(const f32x4*)(Arow + kk + ahalf * 16 + 0);
        f32x4 av1 = *(const f32x4*)(Arow + kk + ahalf * 16 + 4);
        f32x4 av2 = *(const f32x4*)(Arow + kk + ahalf * 16 + 8);
        f32x4 av3 = *(const f32x4*)(Arow + kk + ahalf * 16 + 12);
        f32x4 bv0 = *(const f32x4*)(Bp + (size_t)(kk + bk4 + 0) * ldb + n0 + bn4);
        f32x4 bv1 = *(const f32x4*)(Bp + (size_t)(kk + bk4 + 1) * ldb + n0 + bn4);
        f32x4 bv2 = *(const f32x4*)(Bp + (size_t)(kk + bk4 + 2) * ldb + n0 + bn4);
        f32x4 bv3 = *(const f32x4*)(Bp + (size_t)(kk + bk4 + 3) * ldb + n0 + bn4);

        // ---- split-convert A: 16 k-elems -> two 8-elem slots (hi & lo) ----
        short8 ah0, ah1, al0, al1;
        short th, tl;
#pragma unroll
        for (int i = 0; i < 4; ++i) {
            SPLIT(av0[i], th, tl); ah0[i]     = th; al0[i]     = tl;
            SPLIT(av1[i], th, tl); ah0[i + 4] = th; al0[i + 4] = tl;
            SPLIT(av2[i], th, tl); ah1[i]     = th; al1[i]     = tl;
            SPLIT(av3[i], th, tl); ah1[i + 4] = th; al1[i + 4] = tl;
        }

        __syncthreads();                      // all waves done reading prev tile

        {   // A writes: 16B slots, swizzled
            int s0 = ahalf * 2;
            int x  = (arow >> 2) & 3;
            int o0 = arow * 32 + ((s0 ^ x) * 8);
            int o1 = arow * 32 + (((s0 + 1) ^ x) * 8);
            *(short8*)&AsHi[o0] = ah0;  *(short8*)&AsHi[o1] = ah1;
            *(short8*)&AsLo[o0] = al0;  *(short8*)&AsLo[o1] = al1;
        }
        {   // B writes: transpose 4x4 in regs, b64 per n-row (8B half-slots)
            int s16  = bk4 >> 3;              // 16B slot within row
            int half = (bk4 >> 2) & 1;        // 8B half within slot
#pragma unroll
            for (int c = 0; c < 4; ++c) {
                short4v h4, l4;
                short hh, ll;
                SPLIT(bv0[c], hh, ll); h4[0] = hh; l4[0] = ll;
                SPLIT(bv1[c], hh, ll); h4[1] = hh; l4[1] = ll;
                SPLIT(bv2[c], hh, ll); h4[2] = hh; l4[2] = ll;
                SPLIT(bv3[c], hh, ll); h4[3] = hh; l4[3] = ll;
                int n = bn4 + c;
                int o = n * 32 + ((s16 ^ ((n >> 2) & 3)) * 8) + half * 4;
                *(short4v*)&BsHi[o] = h4;
                *(short4v*)&BsLo[o] = l4;
            }
        }
        __syncthreads();                      // tile ready

        // ---- fragment reads (ds_read_b128, swizzle-matched) + 48 MFMA ----
        short8 Ah[4], Al[4], Bh[4], Bl[4];
#pragma unroll
        for (int f = 0; f < 4; ++f) {
            int r  = wr * 64 + f * 16 + fr;
            int oa = r * 32 + ((fq ^ ((r >> 2) & 3)) * 8);
            Ah[f] = *(const short8*)&AsHi[oa];
            Al[f] = *(const short8*)&AsLo[oa];
            int c  = wc * 64 + f * 16 + fr;
            int ob = c * 32 + ((fq ^ ((c >> 2) & 3)) * 8);
            Bh[f] = *(const short8*)&BsHi[ob];
            Bl[f] = *(const short8*)&BsLo[ob];
        }
#pragma unroll
        for (int mf = 0; mf < 4; ++mf)
#pragma unroll
            for (int nf = 0; nf < 4; ++nf) {
                acc[mf][nf] = __builtin_amdgcn_mfma_f32_16x16x32_bf16(
                    Ah[mf], Bh[nf], acc[mf][nf], 0, 0, 0);
                acc[mf][nf] = __builtin_amdgcn_mfma_f32_16x16x32_bf16(
                    Ah[mf], Bl[nf], acc[mf][nf], 0, 0, 0);
                acc[mf][nf] = __builtin_amdgcn_mfma_f32_16x16x32_bf16(
                    Al[mf], Bh[nf], acc[mf][nf], 0, 0, 0);
            }
    }

    // ---- epilogue: C/D layout col = lane&15, row = (lane>>4)*4 + reg ----
#pragma unroll
    for (int nf = 0; nf < 4; ++nf) {
        int col = n0 + wc * 64 + nf * 16 + fr;
        float bv = 0.f;
        if constexpr (EPI == 1) bv = bias[(size_t)e * FF + col];
#pragma unroll
        for (int mf = 0; mf < 4; ++mf) {
#pragma unroll
            for (int j = 0; j < 4; ++j) {
                int ls = wr * 64 + mf * 16 + fq * 4 + j;   // local row slot
                int s  = m0 + ls;
                if (s < cn) {
                    if constexpr (EPI == 1) {
                        float v = acc[mf][nf][j] + bv;
                        float g = 0.5f * v * (1.f + erff(v * 0.70710678118654752f));
                        Cbase[(size_t)(of + s) * FF + col] = g;
                    } else {
                        atomicAdd(&Cbase[(size_t)blkTok[ls] * DD + col],
                                  acc[mf][nf][j] * blkW[ls]);
                    }
                }
            }
        }
    }
}

// ---------------------------------------------------------------------------
// fp32 proj GEMM (routing input must stay fp32-exact for top-k stability).
// Punning fixed: vector regs accessed by constant-index components only.
// ---------------------------------------------------------------------------
__global__ __launch_bounds__(256)
void proj_gemm(const float* __restrict__ A, const float* __restrict__ B,
               const float* __restrict__ bias, float* __restrict__ C)
{
    const int m0 = blockIdx.x * 128;
    const int n0 = blockIdx.y * 128;

    __shared__ __align__(16) float As[8][128];
    __shared__ __align__(16) float Bs[8][128];

    const int tid = threadIdx.x;
    const int tx = tid & 15, ty = tid >> 4;
    const int arow = tid >> 1, akq = (tid & 1) * 4;
    const int brow = tid >> 5, bn4 = (tid & 31) * 4;

    const float* Arow = A + (size_t)(m0 + arow) * DD;
    const float* Brow = B + (size_t)brow * DD + n0 + bn4;

    float acc[8][8];
#pragma unroll
    for (int i = 0; i < 8; ++i)
#pragma unroll
        for (int j = 0; j < 8; ++j) acc[i][j] = 0.f;

    for (int kk = 0; kk < DD; kk += 8) {
        f32x4 a4 = *(const f32x4*)(Arow + kk + akq);
        f32x4 b4 = *(const f32x4*)(Brow + (size_t)kk * DD);
        __syncthreads();
        As[akq + 0][arow] = a4[0];
        As[akq + 1][arow] = a4[1];
        As[akq + 2][arow] = a4[2];
        As[akq + 3][arow] = a4[3];
        *(f32x4*)&Bs[brow][bn4] = b4;
        __syncthreads();
#pragma unroll
        for (int k = 0; k < 8; ++k) {
            f32x4 a0 = *(const f32x4*)&As[k][ty * 8];
            f32x4 a1 = *(const f32x4*)&As[k][ty * 8 + 4];
            f32x4 b0 = *(const f32x4*)&Bs[k][tx * 8];
            f32x4 b1 = *(const f32x4*)&Bs[k][tx * 8 + 4];
#pragma unroll
            for (int i = 0; i < 4; ++i)
#pragma unroll
                for (int j = 0; j < 4; ++j) {
                    acc[i][j]         = fmaf(a0[i], b0[j], acc[i][j]);
                    acc[i][j + 4]     = fmaf(a0[i], b1[j], acc[i][j + 4]);
                    acc[i + 4][j]     = fmaf(a1[i], b0[j], acc[i + 4][j]);
                    acc[i + 4][j + 4] = fmaf(a1[i], b1[j], acc[i + 4][j + 4]);
                }
        }
    }
#pragma unroll
    for (int i = 0; i < 8; ++i) {
        int m = m0 + ty * 8 + i;
        float* Crow = C + (size_t)m * DD + n0 + tx * 8;
        f32x4 c0, c1;
#pragma unroll
        for (int j = 0; j < 4; ++j) {
            c0[j] = acc[i][j]     + bias[n0 + tx * 8 + j];
            c1[j] = acc[i][j + 4] + bias[n0 + tx * 8 + 4 + j];
        }
        *(f32x4*)(Crow + 0) = c0;
        *(f32x4*)(Crow + 4) = c1;
    }
}

// ---------------------------------------------------------------------------
// Routing: one wave per token, fp32 throughout (top-k selection must be exact).
// ---------------------------------------------------------------------------
__global__ __launch_bounds__(256)
void route_kernel(const float* __restrict__ P, const float* __restrict__ cent,
                  int* __restrict__ cnt, int* __restrict__ list_token,
                  float* __restrict__ list_w, int* __restrict__ tok_e,
                  float* __restrict__ tok_w)
{
    const int lane = threadIdx.x & 63;
    const int wv = threadIdx.x >> 6;
    const int t = blockIdx.x * 4 + wv;
    const float* p = P + (size_t)t * DD;

    float v[16];
    float s = 0.f;
#pragma unroll
    for (int j = 0; j < 4; ++j) {
        f32x4 f = *(const f32x4*)(p + j * 256 + lane * 4);
        v[j * 4 + 0] = f[0]; v[j * 4 + 1] = f[1];
        v[j * 4 + 2] = f[2]; v[j * 4 + 3] = f[3];
        s += f[0] * f[0] + f[1] * f[1] + f[2] * f[2] + f[3] * f[3];
    }
    float cs[EE], dt[EE];
#pragma unroll
    for (int e = 0; e < EE; ++e) {
        const float* c = cent + (size_t)e * DD;
        float cse = 0.f, dte = 0.f;
#pragma unroll
        for (int j = 0; j < 4; ++j) {
            f32x4 f = *(const f32x4*)(c + j * 256 + lane * 4);
            cse += f[0] * f[0] + f[1] * f[1] + f[2] * f[2] + f[3] * f[3];
            dte += f[0] * v[j * 4 + 0] + f[1] * v[j * 4 + 1]
                 + f[2] * v[j * 4 + 2] + f[3] * v[j * 4 + 3];
        }
        cs[e] = cse; dt[e] = dte;
    }
#pragma unroll
    for (int m = 1; m < 64; m <<= 1) {
        s += __shfl_xor(s, m);
#pragma unroll
        for (int e = 0; e < EE; ++e) {
            cs[e] += __shfl_xor(cs[e], m);
            dt[e] += __shfl_xor(dt[e], m);
        }
    }
    float norm = fmaxf(sqrtf(s), EPSF);
    float scale = norm > 0.95f ? 0.95f / norm : 1.0f;
    float xns = fminf(s * scale * scale, 0.99f);

    float best1 = -1e30f, best2 = -1e30f; int i1 = 0, i2 = 0;
#pragma unroll
    for (int e = 0; e < EE; ++e) {
        float cnorm = fmaxf(sqrtf(cs[e]), EPSF);
        float csc = cnorm > 0.95f ? 0.95f / cnorm : 1.0f;
        float cns = fminf(cs[e] * csc * csc, 0.99f);
        float dot = dt[e] * scale * csc;
        float diff = fmaxf(xns + cns - 2.f * dot, 0.f);
        float denom = (1.f - xns) * (1.f - cns) + 1e-7f;
        float arg = fmaxf(1.f + 2.f * diff / denom, 1.f + 1e-7f);
        float lg = -acoshf(arg);
        if (lg > best1) { best2 = best1; i2 = i1; best1 = lg; i1 = e; }
        else if (lg > best2) { best2 = lg; i2 = e; }
    }
    if (lane == 0) {
        float ex = expf(best2 - best1);      // softmax over top-2 (max-sub)
        float inv = 1.f / (1.f + ex);
        int s0 = atomicAdd(&cnt[i1], 1);
        int s1 = atomicAdd(&cnt[i2], 1);
        list_token[i1 * TT + s0] = t; list_w[i1 * TT + s0] = inv;
        list_token[i2 * TT + s1] = t; list_w[i2 * TT + s1] = ex * inv;
        tok_e[2 * t] = i1; tok_e[2 * t + 1] = i2;
        tok_w[2 * t] = inv; tok_w[2 * t + 1] = ex * inv;
    }
}

__global__ void offs_kernel(const int* __restrict__ cnt, int* __restrict__ offs)
{
    if (threadIdx.x == 0 && blockIdx.x == 0) {
        int a = 0;
        for (int e = 0; e < EE; ++e) { offs[e] = a; a += cnt[e]; }
    }
}

// out[t][d] = w0*b2[e0][d] + w1*b2[e1][d]  (overwrites poisoned d_out; experts
// then atomicAdd on top)
__global__ __launch_bounds__(256)
void out_init(const int* __restrict__ tok_e, const float* __restrict__ tok_w,
              const float* __restrict__ b2, float* __restrict__ out)
{
    int idx = blockIdx.x * 256 + threadIdx.x;
    int t = idx >> 8;
    int d = (idx & 255) * 4;
    int e0 = tok_e[2 * t], e1 = tok_e[2 * t + 1];
    float w0 = tok_w[2 * t], w1 = tok_w[2 * t + 1];
    f32x4 a = *(const f32x4*)(b2 + (size_t)e0 * DD + d);
    f32x4 b = *(const f32x4*)(b2 + (size_t)e1 * DD + d);
    f32x4 o;
    o[0] = w0 * a[0] + w1 * b[0];
    o[1] = w0 * a[1] + w1 * b[1];
    o[2] = w0 * a[2] + w1 * b[2];
    o[3] = w0 * a[3] + w1 * b[3];
    *(f32x4*)(out + (size_t)t * DD + d) = o;
}

// ---------------------------------------------------------------------------
extern "C" void kernel_launch(void* const* d_in, const int* in_sizes, int n_in,
                              void* d_out, int out_size, void* d_ws, size_t ws_size,
                              hipStream_t stream)
{
    const float* x    = (const float*)d_in[0];
    const float* cent = (const float*)d_in[1];
    const float* Wp   = (const float*)d_in[2];
    const float* bp   = (const float*)d_in[3];
    const float* W1   = (const float*)d_in[4];
    const float* b1   = (const float*)d_in[5];
    const float* W2   = (const float*)d_in[6];
    const float* b2   = (const float*)d_in[7];
    float* out = (float*)d_out;

    char* ws = (char*)d_ws;
    size_t off = 0;
    float* H          = (float*)(ws + off); off += (size_t)2 * TT * FF * 4; // 134 MB
    float* P          = (float*)(ws + off); off += (size_t)TT * DD * 4;     // 16.8 MB
    int*   list_token = (int*)  (ws + off); off += (size_t)EE * TT * 4;
    float* list_w     = (float*)(ws + off); off += (size_t)EE * TT * 4;
    int*   tok_e      = (int*)  (ws + off); off += (size_t)TT * 2 * 4;
    float* tok_w      = (float*)(ws + off); off += (size_t)TT * 2 * 4;
    int*   cnt        = (int*)  (ws + off); off += 64;
    int*   offs       = (int*)  (ws + off); off += 64;
    if (ws_size < off) return;   // ws too small: leave d_out poisoned -> loud failure

    hipMemsetAsync(cnt, 0, EE * sizeof(int), stream);

    // 1) P = x @ Wp + bp  (fp32: feeds exact top-k)
    proj_gemm<<<dim3(TT / 128, DD / 128, 1), 256, 0, stream>>>(x, Wp, bp, P);
    // 2) hyperbolic routing -> top-2 lists
    route_kernel<<<TT / 4, 256, 0, stream>>>(P, cent, cnt, list_token, list_w,
                                             tok_e, tok_w);
    // 3) per-expert prefix offsets
    offs_kernel<<<1, 64, 0, stream>>>(cnt, offs);
    // 4) out = w0*b2[e0] + w1*b2[e1]
    out_init<<<TT, 256, 0, stream>>>(tok_e, tok_w, b2, out);
    // 5) H = gelu(gather(x) @ W1[e] + b1[e])   (split-bf16 MFMA)
    moe_gemm<1><<<dim3(TT / 128, FF / 128, EE), 256, 0, stream>>>(
        x, W1, b1, H, list_token, nullptr, cnt, offs, DD, DD, FF);
    // 6) out += w * (H @ W2[e])                (split-bf16 MFMA, atomic scatter)
    moe_gemm<2><<<dim3(TT / 128, DD / 128, EE), 256, 0, stream>>>(
        H, W2, nullptr, out, list_token, list_w, cnt, offs, FF, FF, DD);
}

// Round 3
// 1877.739 us; speedup vs baseline: 2.6945x; 1.4996x over previous
//
#include <hip/hip_runtime.h>
#include <hip/hip_bf16.h>
#include <math.h>

#define TT 4096   // tokens = B*N
#define DD 1024
#define EE 8
#define FF 4096
#define EPSF 1e-7f
#define BSTRIDE ((size_t)DD * FF)   // per-expert weight elements (both W1,W2)

typedef __attribute__((ext_vector_type(4))) float  f32x4;
typedef __attribute__((ext_vector_type(8))) short  short8;   // 8 bf16 = MFMA A/B frag
typedef __attribute__((ext_vector_type(4))) short  short4v;

__device__ __forceinline__ unsigned short bf16_rne(float f) {
    unsigned u = __float_as_uint(f);
    return (unsigned short)((u + 0x7fffu + ((u >> 16) & 1u)) >> 16);
}
__device__ __forceinline__ float bf16f(unsigned short h) {
    return __uint_as_float(((unsigned)h) << 16);
}

// async 16B global->LDS (DMA, no VGPR round-trip). LDS dst must be the
// wave-uniform base; HW scatters lane i at dst + i*16.
__device__ __forceinline__ void gload16(const unsigned short* g, unsigned short* l) {
    __builtin_amdgcn_global_load_lds(
        (const __attribute__((address_space(1))) unsigned int*)(const void*)g,
        (__attribute__((address_space(3))) unsigned int*)(void*)l,
        16, 0, 0);
}

// ---------------------------------------------------------------------------
// Grouped bf16 MFMA GEMM, m97 structure: 128x128 tile, BK=32, 4 waves (2x2),
// wave 64x64 = 4x4 frags of 16x16x32, global_load_lds width-16 staging,
// 2 barriers per K-step. Inputs pre-converted bf16; B pre-transposed [n][k].
// EPI 1 (3-pass: AhBh+AhBl+AlBh): H[of+s][n] = gelu(x[list]@W1e + b1e), bf16-hi
// EPI 2 (2-pass: AhBh+AhBl, split-K2): atomicAdd(out[tok][n], w * (Hh@W2e))
// ---------------------------------------------------------------------------
template<int EPI>
__global__ __launch_bounds__(256, 2)
void moe_mfma(const unsigned short* __restrict__ Ah_g,
              const unsigned short* __restrict__ Al_g,
              const unsigned short* __restrict__ Bh_g,
              const unsigned short* __restrict__ Bl_g,
              const float* __restrict__ bias, float* __restrict__ outp,
              unsigned short* __restrict__ Hh,
              const int* __restrict__ list_token, const float* __restrict__ list_w,
              const int* __restrict__ cnt, const int* __restrict__ offs, int e0)
{
    constexpr int LDA  = (EPI == 1) ? DD : FF;   // A row length (k elems)
    constexpr int KLOC = (EPI == 1) ? DD : FF / 2;  // per-block K range (E2: split-K2)

    const int ze = blockIdx.z;
    const int e  = e0 + ze;
    const int cn = cnt[e], of = offs[e];
    const int m0 = blockIdx.x * 128;
    if (m0 >= cn) return;                         // uniform early exit
    int n0, k0;
    if constexpr (EPI == 1) { n0 = blockIdx.y * 128; k0 = 0; }
    else { n0 = (blockIdx.y & 7) * 128; k0 = (blockIdx.y >> 3) * KLOC; }

    __shared__ unsigned short Ah_s[128 * 32];
    __shared__ unsigned short Al_s[(EPI == 1) ? 128 * 32 : 32];
    __shared__ unsigned short Bh_s[128 * 32];
    __shared__ unsigned short Bl_s[128 * 32];
    __shared__ int   blkTok[(EPI == 2) ? 128 : 1];
    __shared__ float blkW[(EPI == 2) ? 128 : 1];

    const int tid  = threadIdx.x;
    const int srow = tid >> 2;            // staging row 0..63 (+64 for issue 1)
    const int kEl  = (tid & 3) * 8;       // k-element offset within 32-k row

    // resolve per-thread global A-row pointers (gather for EPI1)
    const unsigned short* pAh[2];
    const unsigned short* pAl[2];
#pragma unroll
    for (int i = 0; i < 2; ++i) {
        int slot = m0 + srow + i * 64; if (slot > cn - 1) slot = cn - 1;
        size_t rb;
        if constexpr (EPI == 1) rb = (size_t)list_token[e * TT + slot] * LDA;
        else                    rb = (size_t)(of + slot) * LDA;
        pAh[i] = Ah_g + rb + kEl;
        if constexpr (EPI == 1) pAl[i] = Al_g + rb + kEl;
    }
    const unsigned short* pB[2];
#pragma unroll
    for (int i = 0; i < 2; ++i)
        pB[i] = Bh_g + (size_t)ze * BSTRIDE + (size_t)(n0 + srow + i * 64) * LDA + kEl;
    const size_t Blo_delta = (size_t)(Bl_g - Bh_g);   // same layout, lo array

    if constexpr (EPI == 2) {
        if (tid < 128) {
            int s = m0 + tid; if (s > cn - 1) s = cn - 1;
            blkTok[tid] = list_token[e * TT + s];
            blkW[tid]   = list_w[e * TT + s];
        }
    }

    const int w  = tid >> 6;              // wave id (uniform in wave)
    const int lane = tid & 63, fr = lane & 15, fq = lane >> 4;
    const int wr = (w >> 1) * 64, wc = (w & 1) * 64;
    unsigned short* dA  = &Ah_s[w * 512];
    unsigned short* dAl = &Al_s[(EPI == 1) ? w * 512 : 0];
    unsigned short* dBh = &Bh_s[w * 512];
    unsigned short* dBl = &Bl_s[w * 512];

    f32x4 acc[4][4];
#pragma unroll
    for (int i = 0; i < 4; ++i)
#pragma unroll
        for (int j = 0; j < 4; ++j) acc[i][j] = (f32x4)0.f;

    for (int kk = 0; kk < KLOC; kk += 32) {
        const int kg = k0 + kk;
        __syncthreads();                  // prev tile fully consumed
        gload16(pAh[0] + kg, dA);
        gload16(pAh[1] + kg, dA + 2048);
        if constexpr (EPI == 1) {
            gload16(pAl[0] + kg, dAl);
            gload16(pAl[1] + kg, dAl + 2048);
        }
        gload16(pB[0] + kg, dBh);
        gload16(pB[1] + kg, dBh + 2048);
        gload16(pB[0] + Blo_delta + kg, dBl);
        gload16(pB[1] + Blo_delta + kg, dBl + 2048);
        __syncthreads();                  // vmcnt(0) drain: tile ready

        short8 fAh[4], fAl[4], fBh[4], fBl[4];
#pragma unroll
        for (int f = 0; f < 4; ++f) {
            int ra = (wr + f * 16 + fr) * 32 + fq * 8;
            fAh[f] = *(const short8*)&Ah_s[ra];
            if constexpr (EPI == 1) fAl[f] = *(const short8*)&Al_s[ra];
            int rb = (wc + f * 16 + fr) * 32 + fq * 8;
            fBh[f] = *(const short8*)&Bh_s[rb];
            fBl[f] = *(const short8*)&Bl_s[rb];
        }
#pragma unroll
        for (int mf = 0; mf < 4; ++mf)
#pragma unroll
            for (int nf = 0; nf < 4; ++nf) {
                acc[mf][nf] = __builtin_amdgcn_mfma_f32_16x16x32_bf16(
                    fAh[mf], fBh[nf], acc[mf][nf], 0, 0, 0);
                acc[mf][nf] = __builtin_amdgcn_mfma_f32_16x16x32_bf16(
                    fAh[mf], fBl[nf], acc[mf][nf], 0, 0, 0);
                if constexpr (EPI == 1)
                    acc[mf][nf] = __builtin_amdgcn_mfma_f32_16x16x32_bf16(
                        fAl[mf], fBh[nf], acc[mf][nf], 0, 0, 0);
            }
    }

    // epilogue: C/D layout col = lane&15, row = (lane>>4)*4 + reg  (validated r2)
#pragma unroll
    for (int nf = 0; nf < 4; ++nf) {
        int col = n0 + wc + nf * 16 + fr;
        float bv = 0.f;
        if constexpr (EPI == 1) bv = bias[(size_t)e * FF + col];
#pragma unroll
        for (int mf = 0; mf < 4; ++mf) {
#pragma unroll
            for (int j = 0; j < 4; ++j) {
                int ls = wr + mf * 16 + fq * 4 + j;
                int s  = m0 + ls;
                if (s < cn) {
                    if constexpr (EPI == 1) {
                        float v = acc[mf][nf][j] + bv;
                        float g = 0.5f * v * (1.f + erff(v * 0.70710678118654752f));
                        Hh[(size_t)(of + s) * FF + col] = bf16_rne(g);
                    } else {
                        atomicAdd(&outp[(size_t)blkTok[ls] * DD + col],
                                  acc[mf][nf][j] * blkW[ls]);
                    }
                }
            }
        }
    }
}

// ---------------------------------------------------------------------------
// split+transpose: src fp32 [R][C] (per expert) -> dh/dl bf16 [C][R]
// ---------------------------------------------------------------------------
__global__ __launch_bounds__(256)
void splitT(const float* __restrict__ src, unsigned short* __restrict__ dh,
            unsigned short* __restrict__ dl, int R, int C)
{
    __shared__ unsigned short sh[64][66];
    __shared__ unsigned short sl[64][66];
    const float* s = src + (size_t)blockIdx.z * R * C;
    const size_t dbase = (size_t)blockIdx.z * R * C;
    int r0 = blockIdx.y * 64, c0 = blockIdx.x * 64;
    int t = threadIdx.x;
    int rr = t >> 4, c4 = (t & 15) * 4;
#pragma unroll
    for (int rep = 0; rep < 4; ++rep) {
        int r = rr + rep * 16;
        f32x4 v = *(const f32x4*)(s + (size_t)(r0 + r) * C + c0 + c4);
#pragma unroll
        for (int i = 0; i < 4; ++i) {
            unsigned short hh = bf16_rne(v[i]);
            sh[r][c4 + i] = hh;
            sl[r][c4 + i] = bf16_rne(v[i] - bf16f(hh));
        }
    }
    __syncthreads();
#pragma unroll
    for (int rep = 0; rep < 4; ++rep) {
        int cc = rr + rep * 16;
        short4v h4, l4;
#pragma unroll
        for (int i = 0; i < 4; ++i) {
            h4[i] = (short)sh[c4 + i][cc];
            l4[i] = (short)sl[c4 + i][cc];
        }
        *(short4v*)(dh + dbase + (size_t)(c0 + cc) * R + r0 + c4) = h4;
        *(short4v*)(dl + dbase + (size_t)(c0 + cc) * R + r0 + c4) = l4;
    }
}

// x fp32 -> xh/xl bf16 (no transpose), 8 elems/thread
__global__ __launch_bounds__(256)
void split2(const float* __restrict__ src, unsigned short* __restrict__ dh,
            unsigned short* __restrict__ dl, int n8)
{
    int i = blockIdx.x * 256 + threadIdx.x;
    if (i >= n8) return;
    f32x4 a = *(const f32x4*)(src + (size_t)i * 8);
    f32x4 b = *(const f32x4*)(src + (size_t)i * 8 + 4);
    short8 h, l;
#pragma unroll
    for (int j = 0; j < 4; ++j) {
        unsigned short hh = bf16_rne(a[j]);
        h[j] = (short)hh; l[j] = (short)bf16_rne(a[j] - bf16f(hh));
        unsigned short hb = bf16_rne(b[j]);
        h[4 + j] = (short)hb; l[4 + j] = (short)bf16_rne(b[j] - bf16f(hb));
    }
    *(short8*)(dh + (size_t)i * 8) = h;
    *(short8*)(dl + (size_t)i * 8) = l;
}

// ---------------------------------------------------------------------------
// fp32 proj GEMM (routing must stay fp32-exact for top-k stability)
// ---------------------------------------------------------------------------
__global__ __launch_bounds__(256)
void proj_gemm(const float* __restrict__ A, const float* __restrict__ B,
               const float* __restrict__ bias, float* __restrict__ C)
{
    const int m0 = blockIdx.x * 128;
    const int n0 = blockIdx.y * 128;

    __shared__ __align__(16) float As[8][128];
    __shared__ __align__(16) float Bs[8][128];

    const int tid = threadIdx.x;
    const int tx = tid & 15, ty = tid >> 4;
    const int arow = tid >> 1, akq = (tid & 1) * 4;
    const int brow = tid >> 5, bn4 = (tid & 31) * 4;

    const float* Arow = A + (size_t)(m0 + arow) * DD;
    const float* Brow = B + (size_t)brow * DD + n0 + bn4;

    float acc[8][8];
#pragma unroll
    for (int i = 0; i < 8; ++i)
#pragma unroll
        for (int j = 0; j < 8; ++j) acc[i][j] = 0.f;

    for (int kk = 0; kk < DD; kk += 8) {
        f32x4 a4 = *(const f32x4*)(Arow + kk + akq);
        f32x4 b4 = *(const f32x4*)(Brow + (size_t)kk * DD);
        __syncthreads();
        As[akq + 0][arow] = a4[0];
        As[akq + 1][arow] = a4[1];
        As[akq + 2][arow] = a4[2];
        As[akq + 3][arow] = a4[3];
        *(f32x4*)&Bs[brow][bn4] = b4;
        __syncthreads();
#pragma unroll
        for (int k = 0; k < 8; ++k) {
            f32x4 a0 = *(const f32x4*)&As[k][ty * 8];
            f32x4 a1 = *(const f32x4*)&As[k][ty * 8 + 4];
            f32x4 b0 = *(const f32x4*)&Bs[k][tx * 8];
            f32x4 b1 = *(const f32x4*)&Bs[k][tx * 8 + 4];
#pragma unroll
            for (int i = 0; i < 4; ++i)
#pragma unroll
                for (int j = 0; j < 4; ++j) {
                    acc[i][j]         = fmaf(a0[i], b0[j], acc[i][j]);
                    acc[i][j + 4]     = fmaf(a0[i], b1[j], acc[i][j + 4]);
                    acc[i + 4][j]     = fmaf(a1[i], b0[j], acc[i + 4][j]);
                    acc[i + 4][j + 4] = fmaf(a1[i], b1[j], acc[i + 4][j + 4]);
                }
        }
    }
#pragma unroll
    for (int i = 0; i < 8; ++i) {
        int m = m0 + ty * 8 + i;
        float* Crow = C + (size_t)m * DD + n0 + tx * 8;
        f32x4 c0, c1;
#pragma unroll
        for (int j = 0; j < 4; ++j) {
            c0[j] = acc[i][j]     + bias[n0 + tx * 8 + j];
            c1[j] = acc[i][j + 4] + bias[n0 + tx * 8 + 4 + j];
        }
        *(f32x4*)(Crow + 0) = c0;
        *(f32x4*)(Crow + 4) = c1;
    }
}

// ---------------------------------------------------------------------------
// Routing: one wave per token, fp32 throughout.
// ---------------------------------------------------------------------------
__global__ __launch_bounds__(256)
void route_kernel(const float* __restrict__ P, const float* __restrict__ cent,
                  int* __restrict__ cnt, int* __restrict__ list_token,
                  float* __restrict__ list_w, int* __restrict__ tok_e,
                  float* __restrict__ tok_w)
{
    const int lane = threadIdx.x & 63;
    const int wv = threadIdx.x >> 6;
    const int t = blockIdx.x * 4 + wv;
    const float* p = P + (size_t)t * DD;

    float v[16];
    float s = 0.f;
#pragma unroll
    for (int j = 0; j < 4; ++j) {
        f32x4 f = *(const f32x4*)(p + j * 256 + lane * 4);
        v[j * 4 + 0] = f[0]; v[j * 4 + 1] = f[1];
        v[j * 4 + 2] = f[2]; v[j * 4 + 3] = f[3];
        s += f[0] * f[0] + f[1] * f[1] + f[2] * f[2] + f[3] * f[3];
    }
    float cs[EE], dt[EE];
#pragma unroll
    for (int e = 0; e < EE; ++e) {
        const float* c = cent + (size_t)e * DD;
        float cse = 0.f, dte = 0.f;
#pragma unroll
        for (int j = 0; j < 4; ++j) {
            f32x4 f = *(const f32x4*)(c + j * 256 + lane * 4);
            cse += f[0] * f[0] + f[1] * f[1] + f[2] * f[2] + f[3] * f[3];
            dte += f[0] * v[j * 4 + 0] + f[1] * v[j * 4 + 1]
                 + f[2] * v[j * 4 + 2] + f[3] * v[j * 4 + 3];
        }
        cs[e] = cse; dt[e] = dte;
    }
#pragma unroll
    for (int m = 1; m < 64; m <<= 1) {
        s += __shfl_xor(s, m);
#pragma unroll
        for (int e = 0; e < EE; ++e) {
            cs[e] += __shfl_xor(cs[e], m);
            dt[e] += __shfl_xor(dt[e], m);
        }
    }
    float norm = fmaxf(sqrtf(s), EPSF);
    float scale = norm > 0.95f ? 0.95f / norm : 1.0f;
    float xns = fminf(s * scale * scale, 0.99f);

    float best1 = -1e30f, best2 = -1e30f; int i1 = 0, i2 = 0;
#pragma unroll
    for (int e = 0; e < EE; ++e) {
        float cnorm = fmaxf(sqrtf(cs[e]), EPSF);
        float csc = cnorm > 0.95f ? 0.95f / cnorm : 1.0f;
        float cns = fminf(cs[e] * csc * csc, 0.99f);
        float dot = dt[e] * scale * csc;
        float diff = fmaxf(xns + cns - 2.f * dot, 0.f);
        float denom = (1.f - xns) * (1.f - cns) + 1e-7f;
        float arg = fmaxf(1.f + 2.f * diff / denom, 1.f + 1e-7f);
        float lg = -acoshf(arg);
        if (lg > best1) { best2 = best1; i2 = i1; best1 = lg; i1 = e; }
        else if (lg > best2) { best2 = lg; i2 = e; }
    }
    if (lane == 0) {
        float ex = expf(best2 - best1);
        float inv = 1.f / (1.f + ex);
        int s0 = atomicAdd(&cnt[i1], 1);
        int s1 = atomicAdd(&cnt[i2], 1);
        list_token[i1 * TT + s0] = t; list_w[i1 * TT + s0] = inv;
        list_token[i2 * TT + s1] = t; list_w[i2 * TT + s1] = ex * inv;
        tok_e[2 * t] = i1; tok_e[2 * t + 1] = i2;
        tok_w[2 * t] = inv; tok_w[2 * t + 1] = ex * inv;
    }
}

__global__ void offs_kernel(const int* __restrict__ cnt, int* __restrict__ offs)
{
    if (threadIdx.x == 0 && blockIdx.x == 0) {
        int a = 0;
        for (int e = 0; e < EE; ++e) { offs[e] = a; a += cnt[e]; }
    }
}

__global__ __launch_bounds__(256)
void out_init(const int* __restrict__ tok_e, const float* __restrict__ tok_w,
              const float* __restrict__ b2, float* __restrict__ out)
{
    int idx = blockIdx.x * 256 + threadIdx.x;
    int t = idx >> 8;
    int d = (idx & 255) * 4;
    int e0 = tok_e[2 * t], e1 = tok_e[2 * t + 1];
    float w0 = tok_w[2 * t], w1 = tok_w[2 * t + 1];
    f32x4 a = *(const f32x4*)(b2 + (size_t)e0 * DD + d);
    f32x4 b = *(const f32x4*)(b2 + (size_t)e1 * DD + d);
    f32x4 o;
    o[0] = w0 * a[0] + w1 * b[0];
    o[1] = w0 * a[1] + w1 * b[1];
    o[2] = w0 * a[2] + w1 * b[2];
    o[3] = w0 * a[3] + w1 * b[3];
    *(f32x4*)(out + (size_t)t * DD + d) = o;
}

// ---------------------------------------------------------------------------
extern "C" void kernel_launch(void* const* d_in, const int* in_sizes, int n_in,
                              void* d_out, int out_size, void* d_ws, size_t ws_size,
                              hipStream_t stream)
{
    const float* x    = (const float*)d_in[0];
    const float* cent = (const float*)d_in[1];
    const float* Wp   = (const float*)d_in[2];
    const float* bp   = (const float*)d_in[3];
    const float* W1   = (const float*)d_in[4];
    const float* b1   = (const float*)d_in[5];
    const float* W2   = (const float*)d_in[6];
    const float* b2   = (const float*)d_in[7];
    float* out = (float*)d_out;

    // ws layout == round-2's proven 151,322,752 B footprint
    char* ws = (char*)d_ws;
    size_t off = 0;
    unsigned short* Hhb = (unsigned short*)(ws + off); off += (size_t)2 * TT * FF * 2; // 67.1 MB
    unsigned short* Wh  = (unsigned short*)(ws + off); off += (size_t)4 * BSTRIDE * 2; // 33.6 MB
    unsigned short* Wl  = (unsigned short*)(ws + off); off += (size_t)4 * BSTRIDE * 2; // 33.6 MB
    unsigned short* xh  = (unsigned short*)(ws + off); off += (size_t)TT * DD * 2;     // 8.4 MB
    unsigned short* xl  = (unsigned short*)(ws + off); off += (size_t)TT * DD * 2;     // 8.4 MB
    int*   list_token = (int*)  (ws + off); off += (size_t)EE * TT * 4;
    float* list_w     = (float*)(ws + off); off += (size_t)EE * TT * 4;
    int*   tok_e      = (int*)  (ws + off); off += (size_t)TT * 2 * 4;
    float* tok_w      = (float*)(ws + off); off += (size_t)TT * 2 * 4;
    int*   cnt        = (int*)  (ws + off); off += 64;
    int*   offs       = (int*)  (ws + off); off += 64;
    float* P = (float*)Hhb;   // alias: P dead before E1 writes Hh
    if (ws_size < off) return;

    hipMemsetAsync(cnt, 0, EE * sizeof(int), stream);

    // pre-convert x once
    split2<<<(TT * DD / 8 + 255) / 256, 256, 0, stream>>>(x, xh, xl, TT * DD / 8);
    // routing (exact fp32)
    proj_gemm<<<dim3(TT / 128, DD / 128, 1), 256, 0, stream>>>(x, Wp, bp, P);
    route_kernel<<<TT / 4, 256, 0, stream>>>(P, cent, cnt, list_token, list_w,
                                             tok_e, tok_w);
    offs_kernel<<<1, 64, 0, stream>>>(cnt, offs);
    out_init<<<TT, 256, 0, stream>>>(tok_e, tok_w, b2, out);

    // experts in 4-expert groups sharing one weight buffer
    for (int g = 0; g < 2; ++g) {
        splitT<<<dim3(FF / 64, DD / 64, 4), 256, 0, stream>>>(
            W1 + (size_t)g * 4 * BSTRIDE, Wh, Wl, DD, FF);
        moe_mfma<1><<<dim3(TT / 128, FF / 128, 4), 256, 0, stream>>>(
            xh, xl, Wh, Wl, b1, nullptr, Hhb, list_token, nullptr, cnt, offs, g * 4);
    }
    for (int g = 0; g < 2; ++g) {
        splitT<<<dim3(DD / 64, FF / 64, 4), 256, 0, stream>>>(
            W2 + (size_t)g * 4 * BSTRIDE, Wh, Wl, FF, DD);
        moe_mfma<2><<<dim3(TT / 128, 16, 4), 256, 0, stream>>>(
            Hhb, nullptr, Wh, Wl, nullptr, out, nullptr, list_token, list_w,
            cnt, offs, g * 4);
    }
}